// Round 7
// baseline (17.611 us; speedup 1.0000x reference)
//
#include <hip/hip_runtime.h>

// DCN cross layer, B x D f32, D = 1024, LAYERS = 3.
// x_{l+1} = x0 * (x_l . w_l) + b_l + x_l
//
// Closed form:
//   d_i = x0 . W_i;  c1 = b0.W1;  c2 = (b0+b1).W2
//   s0 = d0; s1 = (1+s0)d1 + c1; s2 = (1+s0+s1)d2 + c2
//   out = x0*(1+s0+s1+s2) + (b0+b1+b2)
//
// R7: R4's deep-MLP burst + rotating 3-buffer pipeline so reads stay in
// flight through every reduce/store phase (R6 failed because its 4-load
// depth couldn't cover HBM latency; R4's weakness was a dry tail).
// W/b live in registers (preamble hides under the first 8 x-loads).
// NT loads (x unread after this) + NT stores (out unread until validate).

#define DDIM 1024
#define RPW 4

typedef float f32x4 __attribute__((ext_vector_type(4)));

__device__ __forceinline__ float dot4(f32x4 a, f32x4 b) {
    return fmaf(a.x, b.x, fmaf(a.y, b.y, fmaf(a.z, b.z, a.w * b.w)));
}

__global__ __launch_bounds__(256) void CrossLayer_kernel(
    const float* __restrict__ x,
    const float* __restrict__ W,
    const float* __restrict__ bias,
    float* __restrict__ out,
    int B)
{
    const int wave = threadIdx.x >> 6;
    const int lane = threadIdx.x & 63;
    const int wid  = blockIdx.x * 4 + wave;
    const int row0 = wid * RPW;
    if (row0 >= B) return;

    const float* xbase = x   + (size_t)row0 * DDIM;
    float*       obase = out + (size_t)row0 * DDIM;

    f32x4 bufA[4], bufB[4], bufC[4];

    auto load_row = [&](const float* rb, f32x4* v) {
        const f32x4* p = reinterpret_cast<const f32x4*>(rb);
#pragma unroll
        for (int c = 0; c < 4; ++c)
            v[c] = __builtin_nontemporal_load(&p[c * 64 + lane]);
    };

    // rows 0,1 in flight immediately
    load_row(xbase,        bufA);
    load_row(xbase + DDIM, bufB);

    // ---- W/b preamble -> registers (hides under the x-loads) ----
    f32x4 wv0[4], wv1[4], wv2[4], bsum[4];
    float c1 = 0.f, c2 = 0.f;
    {
        const f32x4* w0p = reinterpret_cast<const f32x4*>(W);
        const f32x4* w1p = reinterpret_cast<const f32x4*>(W + DDIM);
        const f32x4* w2p = reinterpret_cast<const f32x4*>(W + 2 * DDIM);
        const f32x4* b0p = reinterpret_cast<const f32x4*>(bias);
        const f32x4* b1p = reinterpret_cast<const f32x4*>(bias + DDIM);
        const f32x4* b2p = reinterpret_cast<const f32x4*>(bias + 2 * DDIM);
#pragma unroll
        for (int c = 0; c < 4; ++c) {
            const int idx = c * 64 + lane;
            wv0[c] = w0p[idx];
            wv1[c] = w1p[idx];
            wv2[c] = w2p[idx];
            f32x4 bv0 = b0p[idx], bv1 = b1p[idx], bv2 = b2p[idx];
            bsum[c] = bv0 + bv1 + bv2;
            c1 += dot4(bv0, wv1[c]);
            f32x4 b01 = bv0 + bv1;
            c2 += dot4(b01, wv2[c]);
        }
#pragma unroll
        for (int off = 32; off > 0; off >>= 1) {
            c1 += __shfl_xor(c1, off, 64);
            c2 += __shfl_xor(c2, off, 64);
        }
    }

    auto compute_store = [&](const f32x4* xv, int r) {
        float d0 = 0.f, d1 = 0.f, d2 = 0.f;
#pragma unroll
        for (int c = 0; c < 4; ++c) {
            d0 += dot4(xv[c], wv0[c]);
            d1 += dot4(xv[c], wv1[c]);
            d2 += dot4(xv[c], wv2[c]);
        }
#pragma unroll
        for (int off = 32; off > 0; off >>= 1) {
            d0 += __shfl_xor(d0, off, 64);
            d1 += __shfl_xor(d1, off, 64);
            d2 += __shfl_xor(d2, off, 64);
        }
        const float t1 = 1.f + d0;
        const float s1 = fmaf(t1, d1, c1);
        const float t2 = t1 + s1;
        const float s2 = fmaf(t2, d2, c2);
        const float alpha = t2 + s2;

        f32x4* orow = reinterpret_cast<f32x4*>(obase + (size_t)r * DDIM);
#pragma unroll
        for (int c = 0; c < 4; ++c) {
            f32x4 o;
            o.x = fmaf(xv[c].x, alpha, bsum[c].x);
            o.y = fmaf(xv[c].y, alpha, bsum[c].y);
            o.z = fmaf(xv[c].z, alpha, bsum[c].z);
            o.w = fmaf(xv[c].w, alpha, bsum[c].w);
            __builtin_nontemporal_store(o, &orow[c * 64 + lane]);
        }
    };

    // rotating pipeline: reads stay in flight through every phase but the last
    load_row(xbase + 2 * DDIM, bufC);   // rows 1,2 outstanding
    compute_store(bufA, 0);
    load_row(xbase + 3 * DDIM, bufA);   // rows 2?,3 outstanding
    compute_store(bufB, 1);
    compute_store(bufC, 2);             // row 3 outstanding
    compute_store(bufA, 3);             // tail (dry)
}

extern "C" void kernel_launch(void* const* d_in, const int* in_sizes, int n_in,
                              void* d_out, int out_size, void* d_ws, size_t ws_size,
                              hipStream_t stream) {
    const float* x  = (const float*)d_in[0];
    const float* W  = (const float*)d_in[1];
    const float* b  = (const float*)d_in[2];
    float* out      = (float*)d_out;

    const int B = in_sizes[0] / DDIM;              // 8192
    const int rows_per_block = 4 * RPW;            // 16
    dim3 grid((B + rows_per_block - 1) / rows_per_block), block(256);
    hipLaunchKernelGGL(CrossLayer_kernel, grid, block, 0, stream,
                       x, W, b, out, B);
}

// Round 8
// 16.101 us; speedup vs baseline: 1.0938x; 1.0938x over previous
//
#include <hip/hip_runtime.h>

// DCN cross layer, B x D f32, D = 1024, LAYERS = 3.
// x_{l+1} = x0 * (x_l . w_l) + b_l + x_l
//
// Closed form:
//   d_i = x0 . W_i;  c1 = b0.W1;  c2 = (b0+b1).W2
//   s0 = d0; s1 = (1+s0)d1 + c1; s2 = (1+s0+s1)d2 + c2
//   out = x0*(1+s0+s1+s2) + (b0+b1+b2)
//
// R8: HIGH-OCCUPANCY variant. W/b live in LDS (24 KB, staged once per
// block), x rows in registers (RPW=2 -> 32 VGPR). __launch_bounds__(256,8)
// targets <=64 VGPR -> 8 waves/SIMD (2x R4). Per-row VMEM is a pure
// stream: 4 loads + 4 NT stores. TLP (not per-wave pipelining) hides HBM
// latency, like the 82-86%-of-BW norm kernels.

#define DDIM 1024
#define RPW 2      // rows per wave; block = 4 waves -> 8 rows/block

typedef float f32x4 __attribute__((ext_vector_type(4)));

__device__ __forceinline__ float dot4(f32x4 a, f32x4 b) {
    return fmaf(a.x, b.x, fmaf(a.y, b.y, fmaf(a.z, b.z, a.w * b.w)));
}

__global__ __launch_bounds__(256, 8) void CrossLayer_kernel(
    const float* __restrict__ x,
    const float* __restrict__ W,
    const float* __restrict__ bias,
    float* __restrict__ out,
    int B)
{
    __shared__ f32x4 lw0[256], lw1[256], lw2[256];
    __shared__ f32x4 lb0[256], lb1[256], lbs[256];

    const int tid  = threadIdx.x;
    const int wave = tid >> 6;
    const int lane = tid & 63;
    const int row0 = blockIdx.x * (4 * RPW) + wave * RPW;

    // ---- x loads first: deepest-latency (HBM) requests in flight ASAP ----
    f32x4 xr[RPW][4];
    {
        const f32x4* xp = reinterpret_cast<const f32x4*>(x + (size_t)row0 * DDIM);
#pragma unroll
        for (int r = 0; r < RPW; ++r)
#pragma unroll
            for (int c = 0; c < 4; ++c)
                xr[r][c] = xp[r * 256 + c * 64 + lane];
    }

    // ---- cooperative W/b stage into LDS (L2-hot after the first blocks) ----
    {
        const f32x4* w0p = reinterpret_cast<const f32x4*>(W);
        const f32x4* w1p = reinterpret_cast<const f32x4*>(W + DDIM);
        const f32x4* w2p = reinterpret_cast<const f32x4*>(W + 2 * DDIM);
        const f32x4* b0p = reinterpret_cast<const f32x4*>(bias);
        const f32x4* b1p = reinterpret_cast<const f32x4*>(bias + DDIM);
        const f32x4* b2p = reinterpret_cast<const f32x4*>(bias + 2 * DDIM);
        f32x4 a0 = w0p[tid], a1 = w1p[tid], a2 = w2p[tid];
        f32x4 v0 = b0p[tid], v1 = b1p[tid], v2 = b2p[tid];
        lw0[tid] = a0; lw1[tid] = a1; lw2[tid] = a2;
        lb0[tid] = v0; lb1[tid] = v1; lbs[tid] = v0 + v1 + v2;
    }
    __syncthreads();

    // ---- per-wave c1/c2 from LDS ----
    float c1 = 0.f, c2 = 0.f;
#pragma unroll
    for (int c = 0; c < 4; ++c) {
        const int idx = c * 64 + lane;
        f32x4 b0v = lb0[idx], b1v = lb1[idx];
        c1 += dot4(b0v, lw1[idx]);
        c2 += dot4(b0v + b1v, lw2[idx]);
    }

    // ---- dots: one LDS read of W serves both rows ----
    float d[RPW][3];
#pragma unroll
    for (int r = 0; r < RPW; ++r) { d[r][0] = d[r][1] = d[r][2] = 0.f; }
#pragma unroll
    for (int c = 0; c < 4; ++c) {
        const int idx = c * 64 + lane;
        f32x4 w0v = lw0[idx], w1v = lw1[idx], w2v = lw2[idx];
#pragma unroll
        for (int r = 0; r < RPW; ++r) {
            d[r][0] += dot4(xr[r][c], w0v);
            d[r][1] += dot4(xr[r][c], w1v);
            d[r][2] += dot4(xr[r][c], w2v);
        }
    }

    // ---- one butterfly round over 8 independent values ----
#pragma unroll
    for (int off = 32; off > 0; off >>= 1) {
        c1 += __shfl_xor(c1, off, 64);
        c2 += __shfl_xor(c2, off, 64);
#pragma unroll
        for (int r = 0; r < RPW; ++r) {
            d[r][0] += __shfl_xor(d[r][0], off, 64);
            d[r][1] += __shfl_xor(d[r][1], off, 64);
            d[r][2] += __shfl_xor(d[r][2], off, 64);
        }
    }

    // ---- scalar recurrences ----
    float alpha[RPW];
#pragma unroll
    for (int r = 0; r < RPW; ++r) {
        const float t1 = 1.f + d[r][0];
        const float s1 = fmaf(t1, d[r][1], c1);
        const float t2 = t1 + s1;
        const float s2 = fmaf(t2, d[r][2], c2);
        alpha[r] = t2 + s2;
    }

    // ---- epilogue: out = x0*alpha + bsum (bsum from LDS), NT stores ----
    f32x4* op = reinterpret_cast<f32x4*>(out + (size_t)row0 * DDIM);
#pragma unroll
    for (int c = 0; c < 4; ++c) {
        const int idx = c * 64 + lane;
        f32x4 bs = lbs[idx];
#pragma unroll
        for (int r = 0; r < RPW; ++r) {
            f32x4 o;
            o.x = fmaf(xr[r][c].x, alpha[r], bs.x);
            o.y = fmaf(xr[r][c].y, alpha[r], bs.y);
            o.z = fmaf(xr[r][c].z, alpha[r], bs.z);
            o.w = fmaf(xr[r][c].w, alpha[r], bs.w);
            __builtin_nontemporal_store(o, &op[r * 256 + idx]);
        }
    }
}

extern "C" void kernel_launch(void* const* d_in, const int* in_sizes, int n_in,
                              void* d_out, int out_size, void* d_ws, size_t ws_size,
                              hipStream_t stream) {
    const float* x  = (const float*)d_in[0];
    const float* W  = (const float*)d_in[1];
    const float* b  = (const float*)d_in[2];
    float* out      = (float*)d_out;

    const int B = in_sizes[0] / DDIM;              // 8192
    const int rows_per_block = 4 * RPW;            // 8
    dim3 grid((B + rows_per_block - 1) / rows_per_block), block(256);
    hipLaunchKernelGGL(CrossLayer_kernel, grid, block, 0, stream,
                       x, W, b, out, B);
}

// Round 9
// 14.982 us; speedup vs baseline: 1.1755x; 1.0747x over previous
//
#include <hip/hip_runtime.h>

// DCN cross layer, B x D f32, D = 1024, LAYERS = 3.
// x_{l+1} = x0 * (x_l . w_l) + b_l + x_l
//
// Closed form:
//   d_i = x0 . W_i;  c1 = b0.W1;  c2 = (b0+b1).W2
//   s0 = d0; s1 = (1+s0)d1 + c1; s2 = (1+s0+s1)d2 + c2
//   out = x0*(1+s0+s1+s2) + (b0+b1+b2)
//
// FINAL (= R4, best of 7 structural variants at 14.1 us):
// 4 rows per wave. All 16 HBM x-loads issued up front (deep MLP, the
// dominant lever); W/b read once per wave batch (L1-hot) and amortized
// over 4 rows; bsum register-cached for the epilogue; NT streaming
// stores. Tested and rejected: register-persistent W/b + 2-deep pipeline
// (16.5), rotating 3-buffer pipeline + NT loads (17.6), LDS W/b at
// 8 waves/SIMD (16.1), RPW=2 (14.4). Memory-bound: 67 MB mandatory
// traffic at ~4.8 TB/s = 76% of measured copy ceiling.

#define DDIM 1024
#define RPW 4

typedef float f32x4 __attribute__((ext_vector_type(4)));

__device__ __forceinline__ float dot4(f32x4 a, f32x4 b) {
    return fmaf(a.x, b.x, fmaf(a.y, b.y, fmaf(a.z, b.z, a.w * b.w)));
}

__global__ __launch_bounds__(256) void CrossLayer_kernel(
    const float* __restrict__ x,
    const float* __restrict__ W,
    const float* __restrict__ bias,
    float* __restrict__ out,
    int B)
{
    const int wave = threadIdx.x >> 6;
    const int lane = threadIdx.x & 63;
    const int wid  = blockIdx.x * 4 + wave;
    const int row0 = wid * RPW;
    if (row0 >= B) return;

    const f32x4* w0 = reinterpret_cast<const f32x4*>(W);
    const f32x4* w1 = reinterpret_cast<const f32x4*>(W + DDIM);
    const f32x4* w2 = reinterpret_cast<const f32x4*>(W + 2 * DDIM);
    const f32x4* b0 = reinterpret_cast<const f32x4*>(bias);
    const f32x4* b1 = reinterpret_cast<const f32x4*>(bias + DDIM);
    const f32x4* b2 = reinterpret_cast<const f32x4*>(bias + 2 * DDIM);

    // ---- issue all HBM loads first (16 dwordx4 in flight) ----
    f32x4 x0[RPW][4];
#pragma unroll
    for (int r = 0; r < RPW; ++r) {
        const f32x4* xr = reinterpret_cast<const f32x4*>(x + (size_t)(row0 + r) * DDIM);
#pragma unroll
        for (int c = 0; c < 4; ++c)
            x0[r][c] = xr[c * 64 + lane];
    }

    // ---- W/b pass (L1-hot), amortized over RPW rows ----
    f32x4 bsum[4];
    float d[RPW][3];
#pragma unroll
    for (int r = 0; r < RPW; ++r) { d[r][0] = d[r][1] = d[r][2] = 0.f; }
    float c1 = 0.f, c2 = 0.f;

#pragma unroll
    for (int c = 0; c < 4; ++c) {
        const int idx = c * 64 + lane;
        f32x4 wv0 = w0[idx], wv1 = w1[idx], wv2 = w2[idx];
        f32x4 bv0 = b0[idx], bv1 = b1[idx], bv2 = b2[idx];
        bsum[c] = bv0 + bv1 + bv2;
        c1 += dot4(bv0, wv1);
        f32x4 b01 = bv0 + bv1;
        c2 += dot4(b01, wv2);
#pragma unroll
        for (int r = 0; r < RPW; ++r) {
            d[r][0] += dot4(x0[r][c], wv0);
            d[r][1] += dot4(x0[r][c], wv1);
            d[r][2] += dot4(x0[r][c], wv2);
        }
    }

    // ---- one butterfly round over 14 independent values ----
#pragma unroll
    for (int off = 32; off > 0; off >>= 1) {
        c1 += __shfl_xor(c1, off, 64);
        c2 += __shfl_xor(c2, off, 64);
#pragma unroll
        for (int r = 0; r < RPW; ++r) {
            d[r][0] += __shfl_xor(d[r][0], off, 64);
            d[r][1] += __shfl_xor(d[r][1], off, 64);
            d[r][2] += __shfl_xor(d[r][2], off, 64);
        }
    }

    // ---- scalar recurrences ----
    float alpha[RPW];
#pragma unroll
    for (int r = 0; r < RPW; ++r) {
        const float t1 = 1.f + d[r][0];
        const float s1 = fmaf(t1, d[r][1], c1);
        const float t2 = t1 + s1;
        const float s2 = fmaf(t2, d[r][2], c2);
        alpha[r] = t2 + s2;
    }

    // ---- epilogue: out = x0*alpha + bsum, streaming stores ----
#pragma unroll
    for (int r = 0; r < RPW; ++r) {
        f32x4* orow = reinterpret_cast<f32x4*>(out + (size_t)(row0 + r) * DDIM);
#pragma unroll
        for (int c = 0; c < 4; ++c) {
            f32x4 o;
            o.x = fmaf(x0[r][c].x, alpha[r], bsum[c].x);
            o.y = fmaf(x0[r][c].y, alpha[r], bsum[c].y);
            o.z = fmaf(x0[r][c].z, alpha[r], bsum[c].z);
            o.w = fmaf(x0[r][c].w, alpha[r], bsum[c].w);
            __builtin_nontemporal_store(o, &orow[c * 64 + lane]);
        }
    }
}

extern "C" void kernel_launch(void* const* d_in, const int* in_sizes, int n_in,
                              void* d_out, int out_size, void* d_ws, size_t ws_size,
                              hipStream_t stream) {
    const float* x  = (const float*)d_in[0];
    const float* W  = (const float*)d_in[1];
    const float* b  = (const float*)d_in[2];
    float* out      = (float*)d_out;

    const int B = in_sizes[0] / DDIM;              // 8192
    const int rows_per_block = 4 * RPW;            // 16
    dim3 grid((B + rows_per_block - 1) / rows_per_block), block(256);
    hipLaunchKernelGGL(CrossLayer_kernel, grid, block, 0, stream,
                       x, W, b, out, B);
}